// Round 5
// baseline (401.271 us; speedup 1.0000x reference)
//
#include <hip/hip_runtime.h>
#include <hip/hip_bf16.h>

#define N_NODES 50000
#define E_EDGES 1600000
#define FN 8
#define FE 8
#define HID 16
#define IH 10
#define NB_SCAN 196   // ceil(50000/256)

// ---------------- workspace layout ----------------
#define I_CNT   0
#define I_OFF   50048
#define I_RANK  100096
#define I_BSUM  1700096
#define I_BBASE 1700352
#define I_TOTAL 1700608
#define F_H     0
#define F_H2    800000
#define F_MSG   1300000
#define F_TOTAL 26900000
#define WS_NEED ((size_t)I_TOTAL*4 + (size_t)F_TOTAL*4)

typedef __attribute__((ext_vector_type(8))) short bf16x8_t;
typedef __attribute__((ext_vector_type(4))) float f32x4_t;

__device__ __forceinline__ unsigned pkbf(float a, float b) {
    union { __hip_bfloat162 v; unsigned u; } r;
    r.v = __hip_bfloat162(__float2bfloat16(a), __float2bfloat16(b));
    return r.u;
}

// ================= CSR build =================
__global__ __launch_bounds__(256) void count_rank_k(
    const int* __restrict__ ei, int* __restrict__ cnt, int* __restrict__ rank)
{
    int e = blockIdx.x * 256 + threadIdx.x;
    if (e >= E_EDGES) return;
    int dst = ei[E_EDGES + e];
    rank[e] = atomicAdd(&cnt[dst], 1);
}

__global__ __launch_bounds__(256) void blocksum_k(
    const int* __restrict__ cnt, int* __restrict__ bsum)
{
    __shared__ int sh[256];
    int t = threadIdx.x;
    int idx = blockIdx.x * 256 + t;
    sh[t] = (idx < N_NODES) ? cnt[idx] : 0;
    __syncthreads();
#pragma unroll
    for (int d = 128; d > 0; d >>= 1) {
        if (t < d) sh[t] += sh[t + d];
        __syncthreads();
    }
    if (t == 0) bsum[blockIdx.x] = sh[0];
}

__global__ __launch_bounds__(256) void scan_bsums_k(
    const int* __restrict__ bsum, int* __restrict__ bbase)
{
    __shared__ int sh[256];
    int t = threadIdx.x;
    int v = (t < NB_SCAN) ? bsum[t] : 0;
    sh[t] = v;
    __syncthreads();
#pragma unroll
    for (int d = 1; d < 256; d <<= 1) {
        int u = (t >= d) ? sh[t - d] : 0;
        __syncthreads();
        sh[t] += u;
        __syncthreads();
    }
    if (t < NB_SCAN) bbase[t] = sh[t] - v;
}

__global__ __launch_bounds__(256) void offsets_k(
    const int* __restrict__ cnt, const int* __restrict__ bbase,
    int* __restrict__ offset)
{
    __shared__ int sh[256];
    int t = threadIdx.x;
    int b = blockIdx.x;
    int idx = b * 256 + t;
    int v = (idx < N_NODES) ? cnt[idx] : 0;
    sh[t] = v;
    __syncthreads();
#pragma unroll
    for (int d = 1; d < 256; d <<= 1) {
        int u = (t >= d) ? sh[t - d] : 0;
        __syncthreads();
        sh[t] += u;
        __syncthreads();
    }
    int incl = sh[t];
    int base = bbase[b];
    if (idx < N_NODES) offset[idx] = base + incl - v;
    if (idx == N_NODES - 1) offset[N_NODES] = base + incl;
}

// ================= helpers =================
__device__ __forceinline__ void load8(const float* __restrict__ p, float v[8]) {
    const float4* q = reinterpret_cast<const float4*>(p);
    float4 a = q[0], b = q[1];
    v[0]=a.x; v[1]=a.y; v[2]=a.z; v[3]=a.w;
    v[4]=b.x; v[5]=b.y; v[6]=b.z; v[7]=b.w;
}

__device__ __forceinline__ void edge_mlp(
    const float eav[FE], const float* __restrict__ w1,
    const float* __restrict__ b1, float u[IH])
{
#pragma unroll
    for (int h = 0; h < IH; ++h) {
        float s = b1[h];
#pragma unroll
        for (int k = 0; k < FE; ++k) s = fmaf(eav[k], w1[k*IH + h], s);
        u[h] = fmaxf(s, 0.f);
    }
}

// ================= conv0 MFMA: features [x(8), u⊗x(80)] pad 96, W [96][16] =================
// A-frag layout in LDS per tile: step s(3), cis(4), row(16) -> 8 bf16 (16B)
__global__ __launch_bounds__(256, 3) void conv0_mfma_k(
    const float* __restrict__ x, const float* __restrict__ ea,
    const int* __restrict__ ei,
    const float* __restrict__ w1, const float* __restrict__ b1,
    const float* __restrict__ w2, const float* __restrict__ b2,
    const int* __restrict__ offset, const int* __restrict__ rank,
    float* __restrict__ msgbuf)          // [E][16]
{
    __shared__ alignas(16) unsigned short feat[16 * 1536];  // 16 tiles x 3KB = 48KB
    __shared__ alignas(16) unsigned short bfrag[3 * 512];   // 3KB
    __shared__ int posArr[256];

    int t = threadIdx.x;
    int e = blockIdx.x * 256 + t;

    // ---- cooperative B-fragment build: bfrag[s*512 + l*8 + j] = W[s*32+(l>>4)*8+j][l&15]
#pragma unroll
    for (int q = 0; q < 6; ++q) {
        int fid = t * 6 + q;                 // 0..1535
        int l   = (fid >> 3) & 63;
        int j   = fid & 7;
        int s   = fid >> 9;
        int k   = s * 32 + ((l >> 4) << 3) + j;
        int o   = l & 15;
        float wv;
        if (k < 8)        wv = b2[k * HID + o];
        else if (k < 88)  { int kk = k - 8; wv = w2[(kk >> 3) * (FN*HID) + (kk & 7) * HID + o]; }
        else              wv = 0.f;
        union { __hip_bfloat16 h; unsigned short us; } cv;
        cv.h = __float2bfloat16(wv);
        bfrag[fid] = cv.us;
    }
    __syncthreads();

    // ---- per-edge feature build (wave-local LDS) ----
    int src = ei[e];
    int dst = ei[E_EDGES + e];
    posArr[t] = offset[dst] + rank[e];

    float eav[FE];
    load8(ea + (size_t)e * FE, eav);
    float u[IH];
    edge_mlp(eav, w1, b1, u);
    float xv[FN];
    load8(x + (size_t)src * FN, xv);

    int m = t >> 4, r = t & 15;
    unsigned* fb = reinterpret_cast<unsigned*>(feat);
    // chunk c: s=c>>2, cis=c&3 -> dword base m*768 + (s*64 + cis*16 + r)*4
#pragma unroll
    for (int c = 0; c < 12; ++c) {
        float v0,v1,v2,v3,v4,v5,v6,v7;
        if (c == 0)      { v0=xv[0];v1=xv[1];v2=xv[2];v3=xv[3];v4=xv[4];v5=xv[5];v6=xv[6];v7=xv[7]; }
        else if (c < 11) { float uh = u[c-1];
                           v0=uh*xv[0];v1=uh*xv[1];v2=uh*xv[2];v3=uh*xv[3];
                           v4=uh*xv[4];v5=uh*xv[5];v6=uh*xv[6];v7=uh*xv[7]; }
        else             { v0=v1=v2=v3=v4=v5=v6=v7=0.f; }
        int base = m*768 + (((c>>2)*64 + (c&3)*16 + r) << 2);
        fb[base+0] = pkbf(v0,v1);
        fb[base+1] = pkbf(v2,v3);
        fb[base+2] = pkbf(v4,v5);
        fb[base+3] = pkbf(v6,v7);
    }

    // ---- MFMA phase: each wave does its 4 tiles ----
    int lane = t & 63, wave = t >> 6;
    bf16x8_t bfr[3];
#pragma unroll
    for (int s = 0; s < 3; ++s)
        bfr[s] = *reinterpret_cast<const bf16x8_t*>(&bfrag[s*512 + lane*8]);

    int col = lane & 15, rg = lane >> 4;
#pragma unroll
    for (int mm = 0; mm < 4; ++mm) {
        int mt = wave * 4 + mm;
        f32x4_t acc = {0.f, 0.f, 0.f, 0.f};
#pragma unroll
        for (int s = 0; s < 3; ++s) {
            bf16x8_t af = *reinterpret_cast<const bf16x8_t*>(
                &feat[mt*1536 + (s*64 + rg*16 + col)*8]);
            acc = __builtin_amdgcn_mfma_f32_16x16x32_bf16(af, bfr[s], acc, 0, 0, 0);
        }
#pragma unroll
        for (int j = 0; j < 4; ++j) {
            int row = rg * 4 + j;
            int pos = posArr[mt*16 + row];
            msgbuf[(size_t)pos * HID + col] = acc[j];
        }
    }
}

// ================= conv1 MFMA: features [h(16), u⊗h(160)] pad 192, W [192][16(10 used)] =================
__global__ __launch_bounds__(128, 2) void conv1_mfma_k(
    const float* __restrict__ hin, const float* __restrict__ ea,
    const int* __restrict__ ei,
    const float* __restrict__ w1, const float* __restrict__ b1,
    const float* __restrict__ w2, const float* __restrict__ b2,
    const int* __restrict__ offset, const int* __restrict__ rank,
    float* __restrict__ msgbuf)          // [E][10]
{
    __shared__ alignas(16) unsigned short feat[8 * 3072];   // 8 tiles x 6KB = 48KB
    __shared__ alignas(16) unsigned short bfrag[6 * 512];   // 6KB
    __shared__ int posArr[128];

    int t = threadIdx.x;
    int e = blockIdx.x * 128 + t;

    // ---- B-frag build: 3072 elems / 128 threads = 24 each
#pragma unroll
    for (int q = 0; q < 24; ++q) {
        int fid = t * 24 + q;                // 0..3071
        int l   = (fid >> 3) & 63;
        int j   = fid & 7;
        int s   = fid >> 9;
        int k   = s * 32 + ((l >> 4) << 3) + j;
        int o   = l & 15;
        float wv = 0.f;
        if (o < IH) {
            if (k < 16)        wv = b2[k * IH + o];
            else if (k < 176)  { int kk = k - 16; wv = w2[(kk >> 4) * (HID*IH) + (kk & 15) * IH + o]; }
        }
        union { __hip_bfloat16 h; unsigned short us; } cv;
        cv.h = __float2bfloat16(wv);
        bfrag[fid] = cv.us;
    }
    __syncthreads();

    int src = ei[e];
    int dst = ei[E_EDGES + e];
    posArr[t] = offset[dst] + rank[e];

    float eav[FE];
    load8(ea + (size_t)e * FE, eav);
    float u[IH];
    edge_mlp(eav, w1, b1, u);
    float hv[HID];
    load8(hin + (size_t)src * HID,     hv);
    load8(hin + (size_t)src * HID + 8, hv + 8);

    int m = t >> 4, r = t & 15;
    unsigned* fb = reinterpret_cast<unsigned*>(feat);
    // chunks c=0..23; c=0,1: h; c=2+2h0: u[h0]*h[0..7]; c=3+2h0: u[h0]*h[8..15]; c=22,23: 0
#pragma unroll
    for (int c = 0; c < 24; ++c) {
        float v[8];
        if (c < 2) {
#pragma unroll
            for (int j = 0; j < 8; ++j) v[j] = hv[c*8 + j];
        } else if (c < 22) {
            float uh = u[(c - 2) >> 1];
            int ib = ((c - 2) & 1) * 8;
#pragma unroll
            for (int j = 0; j < 8; ++j) v[j] = uh * hv[ib + j];
        } else {
#pragma unroll
            for (int j = 0; j < 8; ++j) v[j] = 0.f;
        }
        int base = m*1536 + (((c>>2)*64 + (c&3)*16 + r) << 2);
        fb[base+0] = pkbf(v[0],v[1]);
        fb[base+1] = pkbf(v[2],v[3]);
        fb[base+2] = pkbf(v[4],v[5]);
        fb[base+3] = pkbf(v[6],v[7]);
    }

    // ---- MFMA: 2 waves, 4 tiles each, 6 K-steps ----
    int lane = t & 63, wave = t >> 6;
    int col = lane & 15, rg = lane >> 4;
#pragma unroll
    for (int mm = 0; mm < 4; ++mm) {
        int mt = wave * 4 + mm;
        f32x4_t acc = {0.f, 0.f, 0.f, 0.f};
#pragma unroll
        for (int s = 0; s < 6; ++s) {
            bf16x8_t bf = *reinterpret_cast<const bf16x8_t*>(&bfrag[s*512 + lane*8]);
            bf16x8_t af = *reinterpret_cast<const bf16x8_t*>(
                &feat[mt*3072 + (s*64 + rg*16 + col)*8]);
            acc = __builtin_amdgcn_mfma_f32_16x16x32_bf16(af, bf, acc, 0, 0, 0);
        }
        if (col < IH) {
#pragma unroll
            for (int j = 0; j < 4; ++j) {
                int row = rg * 4 + j;
                int pos = posArr[mt*16 + row];
                msgbuf[(size_t)pos * IH + col] = acc[j];
            }
        }
    }
}

// ================= node0: segmented reduce + root + relu =================
__global__ __launch_bounds__(256) void node0_red_k(
    const float* __restrict__ x, const float* __restrict__ msgbuf,
    const int* __restrict__ offset,
    const float* __restrict__ root, const float* __restrict__ bias,
    float* __restrict__ h)
{
    int idx = blockIdx.x * 256 + threadIdx.x;
    if (idx >= N_NODES * HID) return;
    int n = idx >> 4;
    int o = idx & 15;
    int beg = offset[n], end = offset[n + 1];
    float s = bias[o];
    for (int j = beg; j < end; ++j) s += msgbuf[(size_t)j * HID + o];
    const float* xr = x + (size_t)n * FN;
#pragma unroll
    for (int i = 0; i < FN; ++i) s = fmaf(xr[i], root[i*HID + o], s);
    h[idx] = fmaxf(s, 0.f);
}

// ================= node1: segmented reduce + root + relu =================
__global__ __launch_bounds__(256) void node1_red_k(
    const float* __restrict__ hin, const float* __restrict__ msgbuf,
    const int* __restrict__ offset,
    const float* __restrict__ root, const float* __restrict__ bias,
    float* __restrict__ h2)
{
    int idx = blockIdx.x * 256 + threadIdx.x;
    if (idx >= N_NODES * IH) return;
    int n = idx / IH;
    int o = idx - n * IH;
    int beg = offset[n], end = offset[n + 1];
    float s = bias[o];
    for (int j = beg; j < end; ++j) s += msgbuf[(size_t)j * IH + o];
    const float* hr = hin + (size_t)n * HID;
#pragma unroll
    for (int i = 0; i < HID; ++i) s = fmaf(hr[i], root[i*IH + o], s);
    h2[idx] = fmaxf(s, 0.f);
}

// ================= edge predictor: 1 edge/thread =================
__global__ __launch_bounds__(256) void edge_pred_k(
    const float* __restrict__ h2, const float* __restrict__ ea,
    const int* __restrict__ ei,
    const float* __restrict__ w1, const float* __restrict__ b1,
    const float* __restrict__ w2, const float* __restrict__ b2,
    float* __restrict__ out)
{
    int e = blockIdx.x * 256 + threadIdx.x;
    if (e >= E_EDGES) return;
    int src = ei[e];
    float eav[FE];
    load8(ea + (size_t)e * FE, eav);
    float hv[IH];
    {
        const float2* p = reinterpret_cast<const float2*>(h2 + (size_t)src * IH);
        float2 a = p[0], b = p[1], c = p[2], d = p[3], f = p[4];
        hv[0]=a.x; hv[1]=a.y; hv[2]=b.x; hv[3]=b.y; hv[4]=c.x;
        hv[5]=c.y; hv[6]=d.x; hv[7]=d.y; hv[8]=f.x; hv[9]=f.y;
    }
    float score = b2[0];
#pragma unroll
    for (int j = 0; j < IH; ++j) {
        float s = b1[j];
#pragma unroll
        for (int k = 0; k < FE; ++k) s = fmaf(eav[k], w1[k*IH + j], s);
#pragma unroll
        for (int k = 0; k < IH; ++k) s = fmaf(hv[k], w1[(FE + k)*IH + j], s);
        s = fmaxf(s, 0.f);
        score = fmaf(s, w2[j], score);
    }
    out[e] = score;
}

// ================= fallback (atomic) path =================
__global__ __launch_bounds__(256) void conv0_edge_k(
    const float* __restrict__ x, const float* __restrict__ ea,
    const int* __restrict__ ei,
    const float* __restrict__ w1, const float* __restrict__ b1,
    const float* __restrict__ w2, const float* __restrict__ b2,
    float* __restrict__ agg)
{
    int e = blockIdx.x * 256 + threadIdx.x;
    if (e >= E_EDGES) return;
    int src = ei[e];
    int dst = ei[E_EDGES + e];
    float eav[FE];
    load8(ea + (size_t)e * FE, eav);
    float u[IH];
    edge_mlp(eav, w1, b1, u);
    float xv[FN];
    load8(x + (size_t)src * FN, xv);
    float msg[HID];
#pragma unroll
    for (int o = 0; o < HID; ++o) msg[o] = 0.f;
#pragma unroll
    for (int i = 0; i < FN; ++i) {
        float xi = xv[i];
#pragma unroll
        for (int o = 0; o < HID; ++o) {
            float t = b2[i*HID + o];
#pragma unroll
            for (int h = 0; h < IH; ++h)
                t = fmaf(u[h], w2[h*(FN*HID) + i*HID + o], t);
            msg[o] = fmaf(xi, t, msg[o]);
        }
    }
    float* ap = agg + (size_t)dst * HID;
#pragma unroll
    for (int o = 0; o < HID; ++o) atomicAdd(ap + o, msg[o]);
}

__global__ __launch_bounds__(256) void node0_k(
    const float* __restrict__ x, const float* __restrict__ agg,
    const float* __restrict__ root, const float* __restrict__ bias,
    float* __restrict__ h)
{
    int idx = blockIdx.x * 256 + threadIdx.x;
    if (idx >= N_NODES * HID) return;
    int n = idx >> 4;
    int o = idx & 15;
    float s = agg[idx] + bias[o];
    const float* xr = x + (size_t)n * FN;
#pragma unroll
    for (int i = 0; i < FN; ++i) s = fmaf(xr[i], root[i*HID + o], s);
    h[idx] = fmaxf(s, 0.f);
}

__global__ __launch_bounds__(256) void conv1_edge_k(
    const float* __restrict__ hin, const float* __restrict__ ea,
    const int* __restrict__ ei,
    const float* __restrict__ w1, const float* __restrict__ b1,
    const float* __restrict__ w2, const float* __restrict__ b2,
    float* __restrict__ agg)
{
    int e = blockIdx.x * 256 + threadIdx.x;
    if (e >= E_EDGES) return;
    int src = ei[e];
    int dst = ei[E_EDGES + e];
    float eav[FE];
    load8(ea + (size_t)e * FE, eav);
    float u[IH];
    edge_mlp(eav, w1, b1, u);
    float hv[HID];
    load8(hin + (size_t)src * HID,     hv);
    load8(hin + (size_t)src * HID + 8, hv + 8);
    float msg[IH];
#pragma unroll
    for (int o = 0; o < IH; ++o) msg[o] = 0.f;
#pragma unroll
    for (int i = 0; i < HID; ++i) {
        float hi = hv[i];
#pragma unroll
        for (int o = 0; o < IH; ++o) {
            float t = b2[i*IH + o];
#pragma unroll
            for (int h = 0; h < IH; ++h)
                t = fmaf(u[h], w2[h*(HID*IH) + i*IH + o], t);
            msg[o] = fmaf(hi, t, msg[o]);
        }
    }
    float* ap = agg + (size_t)dst * IH;
#pragma unroll
    for (int o = 0; o < IH; ++o) atomicAdd(ap + o, msg[o]);
}

__global__ __launch_bounds__(256) void node1_k(
    const float* __restrict__ hin, const float* __restrict__ agg,
    const float* __restrict__ root, const float* __restrict__ bias,
    float* __restrict__ h2)
{
    int idx = blockIdx.x * 256 + threadIdx.x;
    if (idx >= N_NODES * IH) return;
    int n = idx / IH;
    int o = idx - n * IH;
    float s = agg[idx] + bias[o];
    const float* hr = hin + (size_t)n * HID;
#pragma unroll
    for (int i = 0; i < HID; ++i) s = fmaf(hr[i], root[i*IH + o], s);
    h2[idx] = fmaxf(s, 0.f);
}

extern "C" void kernel_launch(void* const* d_in, const int* in_sizes, int n_in,
                              void* d_out, int out_size, void* d_ws, size_t ws_size,
                              hipStream_t stream) {
    const float* x       = (const float*)d_in[0];
    const float* ea      = (const float*)d_in[1];
    const int*   ei      = (const int*)  d_in[2];
    const float* c0_w1   = (const float*)d_in[3];
    const float* c0_b1   = (const float*)d_in[4];
    const float* c0_w2   = (const float*)d_in[5];
    const float* c0_b2   = (const float*)d_in[6];
    const float* c0_root = (const float*)d_in[7];
    const float* c0_bias = (const float*)d_in[8];
    const float* c1_w1   = (const float*)d_in[9];
    const float* c1_b1   = (const float*)d_in[10];
    const float* c1_w2   = (const float*)d_in[11];
    const float* c1_b2   = (const float*)d_in[12];
    const float* c1_root = (const float*)d_in[13];
    const float* c1_bias = (const float*)d_in[14];
    const float* ep_w1   = (const float*)d_in[15];
    const float* ep_b1   = (const float*)d_in[16];
    const float* ep_w2   = (const float*)d_in[17];
    const float* ep_b2   = (const float*)d_in[18];
    float* out = (float*)d_out;

    int eb = (E_EDGES + 255) / 256;

    if (ws_size >= WS_NEED) {
        int*   wi     = (int*)d_ws;
        int*   cnt    = wi + I_CNT;
        int*   offset = wi + I_OFF;
        int*   rank   = wi + I_RANK;
        int*   bsum   = wi + I_BSUM;
        int*   bbase  = wi + I_BBASE;
        float* wf     = (float*)(wi + I_TOTAL);
        float* h      = wf + F_H;
        float* h2     = wf + F_H2;
        float* msg    = wf + F_MSG;

        hipMemsetAsync(cnt, 0, N_NODES * sizeof(int), stream);
        count_rank_k<<<eb, 256, 0, stream>>>(ei, cnt, rank);
        blocksum_k<<<NB_SCAN, 256, 0, stream>>>(cnt, bsum);
        scan_bsums_k<<<1, 256, 0, stream>>>(bsum, bbase);
        offsets_k<<<NB_SCAN, 256, 0, stream>>>(cnt, bbase, offset);

        conv0_mfma_k<<<E_EDGES/256, 256, 0, stream>>>(x, ea, ei, c0_w1, c0_b1, c0_w2, c0_b2,
                                                      offset, rank, msg);
        node0_red_k<<<(N_NODES*HID + 255)/256, 256, 0, stream>>>(x, msg, offset,
                                                                 c0_root, c0_bias, h);
        conv1_mfma_k<<<E_EDGES/128, 128, 0, stream>>>(h, ea, ei, c1_w1, c1_b1, c1_w2, c1_b2,
                                                      offset, rank, msg);
        node1_red_k<<<(N_NODES*IH + 255)/256, 256, 0, stream>>>(h, msg, offset,
                                                                c1_root, c1_bias, h2);
        edge_pred_k<<<eb, 256, 0, stream>>>(h2, ea, ei, ep_w1, ep_b1, ep_w2, ep_b2, out);
    } else {
        float* ws   = (float*)d_ws;
        float* agg0 = ws;
        float* agg1 = ws + 800000;
        float* h    = ws + 1300000;
        float* h2   = ws + 2100000;
        hipMemsetAsync(d_ws, 0, 1300000 * sizeof(float), stream);
        conv0_edge_k<<<eb, 256, 0, stream>>>(x, ea, ei, c0_w1, c0_b1, c0_w2, c0_b2, agg0);
        node0_k<<<(N_NODES*HID + 255)/256, 256, 0, stream>>>(x, agg0, c0_root, c0_bias, h);
        conv1_edge_k<<<eb, 256, 0, stream>>>(h, ea, ei, c1_w1, c1_b1, c1_w2, c1_b2, agg1);
        node1_k<<<(N_NODES*IH + 255)/256, 256, 0, stream>>>(h, agg1, c1_root, c1_bias, h2);
        edge_pred_k<<<eb, 256, 0, stream>>>(h2, ea, ei, ep_w1, ep_b1, ep_w2, ep_b2, out);
    }
}

// Round 6
// 343.974 us; speedup vs baseline: 1.1666x; 1.1666x over previous
//
#include <hip/hip_runtime.h>

#define N_NODES 50000
#define E_EDGES 1600000
#define FN 8
#define FE 8
#define HID 16
#define IH 10
#define NB_SCAN 196   // ceil(50000/256)
#define C1_TILE 240

// ---------------- workspace layout ----------------
#define I_CNT   0
#define I_OFF   50048
#define I_RANK  100096
#define I_BSUM  1700096
#define I_BBASE 1700352
#define I_TOTAL 1700608
#define F_H     0
#define F_H2    800000
#define F_MSG   1300000
#define F_TOTAL 26900000
#define WS_NEED ((size_t)I_TOTAL*4 + (size_t)F_TOTAL*4)

// ================= CSR build =================
__global__ __launch_bounds__(256) void count_rank_k(
    const int* __restrict__ ei, int* __restrict__ cnt, int* __restrict__ rank)
{
    int e = blockIdx.x * 256 + threadIdx.x;
    if (e >= E_EDGES) return;
    int dst = ei[E_EDGES + e];
    rank[e] = atomicAdd(&cnt[dst], 1);
}

__global__ __launch_bounds__(256) void blocksum_k(
    const int* __restrict__ cnt, int* __restrict__ bsum)
{
    __shared__ int sh[256];
    int t = threadIdx.x;
    int idx = blockIdx.x * 256 + t;
    sh[t] = (idx < N_NODES) ? cnt[idx] : 0;
    __syncthreads();
#pragma unroll
    for (int d = 128; d > 0; d >>= 1) {
        if (t < d) sh[t] += sh[t + d];
        __syncthreads();
    }
    if (t == 0) bsum[blockIdx.x] = sh[0];
}

__global__ __launch_bounds__(256) void scan_bsums_k(
    const int* __restrict__ bsum, int* __restrict__ bbase)
{
    __shared__ int sh[256];
    int t = threadIdx.x;
    int v = (t < NB_SCAN) ? bsum[t] : 0;
    sh[t] = v;
    __syncthreads();
#pragma unroll
    for (int d = 1; d < 256; d <<= 1) {
        int u = (t >= d) ? sh[t - d] : 0;
        __syncthreads();
        sh[t] += u;
        __syncthreads();
    }
    if (t < NB_SCAN) bbase[t] = sh[t] - v;
}

__global__ __launch_bounds__(256) void offsets_k(
    const int* __restrict__ cnt, const int* __restrict__ bbase,
    int* __restrict__ offset)
{
    __shared__ int sh[256];
    int t = threadIdx.x;
    int b = blockIdx.x;
    int idx = b * 256 + t;
    int v = (idx < N_NODES) ? cnt[idx] : 0;
    sh[t] = v;
    __syncthreads();
#pragma unroll
    for (int d = 1; d < 256; d <<= 1) {
        int u = (t >= d) ? sh[t - d] : 0;
        __syncthreads();
        sh[t] += u;
        __syncthreads();
    }
    int incl = sh[t];
    int base = bbase[b];
    if (idx < N_NODES) offset[idx] = base + incl - v;
    if (idx == N_NODES - 1) offset[N_NODES] = base + incl;
}

// ================= helpers =================
__device__ __forceinline__ void load8(const float* __restrict__ p, float v[8]) {
    const float4* q = reinterpret_cast<const float4*>(p);
    float4 a = q[0], b = q[1];
    v[0]=a.x; v[1]=a.y; v[2]=a.z; v[3]=a.w;
    v[4]=b.x; v[5]=b.y; v[6]=b.z; v[7]=b.w;
}

__device__ __forceinline__ void edge_mlp(
    const float eav[FE], const float* __restrict__ w1,
    const float* __restrict__ b1, float u[IH])
{
#pragma unroll
    for (int h = 0; h < IH; ++h) {
        float s = b1[h];
#pragma unroll
        for (int k = 0; k < FE; ++k) s = fmaf(eav[k], w1[k*IH + h], s);
        u[h] = fmaxf(s, 0.f);
    }
}

// ================= conv0: o-split, weights VGPR-resident =================
// lane owns output column o = t&15; weights (88) pulled from LDS once.
__global__ __launch_bounds__(256) void conv0_osplit_k(
    const float* __restrict__ x, const float* __restrict__ ea,
    const int* __restrict__ ei,
    const float* __restrict__ w1, const float* __restrict__ b1,
    const float* __restrict__ w2, const float* __restrict__ b2,
    const int* __restrict__ offset, const int* __restrict__ rank,
    float* __restrict__ msgbuf)          // [E][16]
{
    __shared__ float wlds[1408];         // [k][o]: k<8 -> b2, k>=8 -> w2
    __shared__ float ulds[256 * 12];     // stride 12 (bank spread)
    __shared__ float xlds[256 * 8];
    __shared__ int   plds[256];

    int t = threadIdx.x;
    // stage weight matrix (both sources are contiguous [k*16+o])
#pragma unroll
    for (int q = 0; q < 6; ++q) {
        int idx = q * 256 + t;
        if (idx < 1408) wlds[idx] = (idx < 128) ? b2[idx] : w2[idx - 128];
    }

    // phase 1: per-edge u, x, pos -> LDS (grid is exact: E/256)
    int e = blockIdx.x * 256 + t;
    {
        int src = ei[e];
        int dst = ei[E_EDGES + e];
        plds[t] = offset[dst] + rank[e];
        float eav[FE];
        load8(ea + (size_t)e * FE, eav);
        float u[IH];
        edge_mlp(eav, w1, b1, u);
        float xv[FN];
        load8(x + (size_t)src * FN, xv);
#pragma unroll
        for (int i = 0; i < FN; ++i) xlds[t*8 + i] = xv[i];
#pragma unroll
        for (int h = 0; h < IH; ++h) ulds[t*12 + h] = u[h];
    }
    __syncthreads();

    // pull this lane's weight column into VGPRs (one-time)
    int o = t & 15, g = t >> 4;
    float wb[8], ww[80];
#pragma unroll
    for (int i = 0; i < 8; ++i)  wb[i] = wlds[i*16 + o];
#pragma unroll
    for (int k = 0; k < 80; ++k) ww[k] = wlds[128 + k*16 + o];

    // phase 2: 16 edges per group-slot
#pragma unroll 2
    for (int j = 0; j < 16; ++j) {
        int eidx = j * 16 + g;
        float xv[8], uv[10];
#pragma unroll
        for (int i = 0; i < 8; ++i)  xv[i] = xlds[eidx*8 + i];
#pragma unroll
        for (int h = 0; h < 10; ++h) uv[h] = ulds[eidx*12 + h];
        float acc = 0.f;
#pragma unroll
        for (int i = 0; i < 8; ++i) acc = fmaf(xv[i], wb[i], acc);
#pragma unroll
        for (int h = 0; h < 10; ++h) {
            float th = 0.f;
#pragma unroll
            for (int i = 0; i < 8; ++i) th = fmaf(xv[i], ww[h*8 + i], th);
            acc = fmaf(uv[h], th, acc);
        }
        msgbuf[(size_t)plds[eidx] * HID + o] = acc;   // 16 lanes -> 64B coalesced
    }
}

// ================= conv1: (o x i-half)-split, weights VGPR-resident =================
// 20 lanes/edge: oo = rem%10, ihalf = rem/10; 3 edges per wave (lanes 0..59).
__global__ __launch_bounds__(256) void conv1_osplit_k(
    const float* __restrict__ hin, const float* __restrict__ ea,
    const int* __restrict__ ei,
    const float* __restrict__ w1, const float* __restrict__ b1,
    const float* __restrict__ w2, const float* __restrict__ b2,
    const int* __restrict__ offset, const int* __restrict__ rank,
    float* __restrict__ msgbuf)          // [E][10]
{
    __shared__ float wlds[1760];         // w2 (1600) then b2 (160)
    __shared__ float ulds[C1_TILE * 12];
    __shared__ float hlds[C1_TILE * 20]; // stride 20 (bank spread, 16B aligned)
    __shared__ int   plds[C1_TILE];

    int t = threadIdx.x;
#pragma unroll
    for (int q = 0; q < 7; ++q) {
        int idx = q * 256 + t;
        if (idx < 1760) wlds[idx] = (idx < 1600) ? w2[idx] : b2[idx - 1600];
    }

    int ebase = blockIdx.x * C1_TILE;
    if (t < C1_TILE) {
        int e = ebase + t;
        int ee = (e < E_EDGES) ? e : 0;
        int src = ei[ee];
        int dst = ei[E_EDGES + ee];
        plds[t] = offset[dst] + rank[ee];
        float eav[FE];
        load8(ea + (size_t)ee * FE, eav);
        float u[IH];
        edge_mlp(eav, w1, b1, u);
        float hv[HID];
        load8(hin + (size_t)src * HID,     hv);
        load8(hin + (size_t)src * HID + 8, hv + 8);
#pragma unroll
        for (int i = 0; i < HID; ++i) hlds[t*20 + i] = hv[i];
#pragma unroll
        for (int h = 0; h < IH; ++h)  ulds[t*12 + h] = u[h];
    }
    __syncthreads();

    int lane = t & 63, wv = t >> 6;
    int esub = lane / 20; if (esub > 2) esub = 2;
    int rem  = lane % 20;
    int oo = rem % 10, ihalf = rem / 10;
    bool active = (lane < 60);
    int partner = active ? (ihalf == 0 ? lane + 10 : lane - 10) : lane;

    // pull weights: column oo, input-half ihalf  (88 VGPR)
    float ww[80], wb[8];
#pragma unroll
    for (int h = 0; h < 10; ++h)
#pragma unroll
        for (int i = 0; i < 8; ++i)
            ww[h*8 + i] = wlds[h*160 + (ihalf*8 + i)*10 + oo];
#pragma unroll
    for (int i = 0; i < 8; ++i) wb[i] = wlds[1600 + (ihalf*8 + i)*10 + oo];

#pragma unroll 2
    for (int j = 0; j < 20; ++j) {
        int eidx = j * 12 + wv * 3 + esub;   // < 240
        float hv[8], uv[10];
#pragma unroll
        for (int i = 0; i < 8; ++i)  hv[i] = hlds[eidx*20 + ihalf*8 + i];
#pragma unroll
        for (int h = 0; h < 10; ++h) uv[h] = ulds[eidx*12 + h];
        float acc = 0.f;
#pragma unroll
        for (int i = 0; i < 8; ++i) acc = fmaf(hv[i], wb[i], acc);
#pragma unroll
        for (int h = 0; h < 10; ++h) {
            float th = 0.f;
#pragma unroll
            for (int i = 0; i < 8; ++i) th = fmaf(hv[i], ww[h*8 + i], th);
            acc = fmaf(uv[h], th, acc);
        }
        float other = __shfl(acc, partner, 64);
        float msgv = acc + other;
        int eg = ebase + eidx;
        if (active && ihalf == 0 && eg < E_EDGES)
            msgbuf[(size_t)plds[eidx] * IH + oo] = msgv;  // 10 lanes -> 40B contiguous
    }
}

// ================= node0: segmented reduce + root + relu =================
__global__ __launch_bounds__(256) void node0_red_k(
    const float* __restrict__ x, const float* __restrict__ msgbuf,
    const int* __restrict__ offset,
    const float* __restrict__ root, const float* __restrict__ bias,
    float* __restrict__ h)
{
    int idx = blockIdx.x * 256 + threadIdx.x;
    if (idx >= N_NODES * HID) return;
    int n = idx >> 4;
    int o = idx & 15;
    int beg = offset[n], end = offset[n + 1];
    float s = bias[o];
    for (int j = beg; j < end; ++j) s += msgbuf[(size_t)j * HID + o];
    const float* xr = x + (size_t)n * FN;
#pragma unroll
    for (int i = 0; i < FN; ++i) s = fmaf(xr[i], root[i*HID + o], s);
    h[idx] = fmaxf(s, 0.f);
}

// ================= node1: segmented reduce + root + relu =================
__global__ __launch_bounds__(256) void node1_red_k(
    const float* __restrict__ hin, const float* __restrict__ msgbuf,
    const int* __restrict__ offset,
    const float* __restrict__ root, const float* __restrict__ bias,
    float* __restrict__ h2)
{
    int idx = blockIdx.x * 256 + threadIdx.x;
    if (idx >= N_NODES * IH) return;
    int n = idx / IH;
    int o = idx - n * IH;
    int beg = offset[n], end = offset[n + 1];
    float s = bias[o];
    for (int j = beg; j < end; ++j) s += msgbuf[(size_t)j * IH + o];
    const float* hr = hin + (size_t)n * HID;
#pragma unroll
    for (int i = 0; i < HID; ++i) s = fmaf(hr[i], root[i*IH + o], s);
    h2[idx] = fmaxf(s, 0.f);
}

// ================= edge predictor: 1 edge/thread =================
__global__ __launch_bounds__(256) void edge_pred_k(
    const float* __restrict__ h2, const float* __restrict__ ea,
    const int* __restrict__ ei,
    const float* __restrict__ w1, const float* __restrict__ b1,
    const float* __restrict__ w2, const float* __restrict__ b2,
    float* __restrict__ out)
{
    int e = blockIdx.x * 256 + threadIdx.x;
    if (e >= E_EDGES) return;
    int src = ei[e];
    float eav[FE];
    load8(ea + (size_t)e * FE, eav);
    float hv[IH];
    {
        const float2* p = reinterpret_cast<const float2*>(h2 + (size_t)src * IH);
        float2 a = p[0], b = p[1], c = p[2], d = p[3], f = p[4];
        hv[0]=a.x; hv[1]=a.y; hv[2]=b.x; hv[3]=b.y; hv[4]=c.x;
        hv[5]=c.y; hv[6]=d.x; hv[7]=d.y; hv[8]=f.x; hv[9]=f.y;
    }
    float score = b2[0];
#pragma unroll
    for (int j = 0; j < IH; ++j) {
        float s = b1[j];
#pragma unroll
        for (int k = 0; k < FE; ++k) s = fmaf(eav[k], w1[k*IH + j], s);
#pragma unroll
        for (int k = 0; k < IH; ++k) s = fmaf(hv[k], w1[(FE + k)*IH + j], s);
        s = fmaxf(s, 0.f);
        score = fmaf(s, w2[j], score);
    }
    out[e] = score;
}

// ================= fallback (atomic) path =================
__global__ __launch_bounds__(256) void conv0_edge_k(
    const float* __restrict__ x, const float* __restrict__ ea,
    const int* __restrict__ ei,
    const float* __restrict__ w1, const float* __restrict__ b1,
    const float* __restrict__ w2, const float* __restrict__ b2,
    float* __restrict__ agg)
{
    int e = blockIdx.x * 256 + threadIdx.x;
    if (e >= E_EDGES) return;
    int src = ei[e];
    int dst = ei[E_EDGES + e];
    float eav[FE];
    load8(ea + (size_t)e * FE, eav);
    float u[IH];
    edge_mlp(eav, w1, b1, u);
    float xv[FN];
    load8(x + (size_t)src * FN, xv);
    float msg[HID];
#pragma unroll
    for (int o = 0; o < HID; ++o) msg[o] = 0.f;
#pragma unroll
    for (int i = 0; i < FN; ++i) {
        float xi = xv[i];
#pragma unroll
        for (int o = 0; o < HID; ++o) {
            float t = b2[i*HID + o];
#pragma unroll
            for (int h = 0; h < IH; ++h)
                t = fmaf(u[h], w2[h*(FN*HID) + i*HID + o], t);
            msg[o] = fmaf(xi, t, msg[o]);
        }
    }
    float* ap = agg + (size_t)dst * HID;
#pragma unroll
    for (int o = 0; o < HID; ++o) atomicAdd(ap + o, msg[o]);
}

__global__ __launch_bounds__(256) void node0_k(
    const float* __restrict__ x, const float* __restrict__ agg,
    const float* __restrict__ root, const float* __restrict__ bias,
    float* __restrict__ h)
{
    int idx = blockIdx.x * 256 + threadIdx.x;
    if (idx >= N_NODES * HID) return;
    int n = idx >> 4;
    int o = idx & 15;
    float s = agg[idx] + bias[o];
    const float* xr = x + (size_t)n * FN;
#pragma unroll
    for (int i = 0; i < FN; ++i) s = fmaf(xr[i], root[i*HID + o], s);
    h[idx] = fmaxf(s, 0.f);
}

__global__ __launch_bounds__(256) void conv1_edge_k(
    const float* __restrict__ hin, const float* __restrict__ ea,
    const int* __restrict__ ei,
    const float* __restrict__ w1, const float* __restrict__ b1,
    const float* __restrict__ w2, const float* __restrict__ b2,
    float* __restrict__ agg)
{
    int e = blockIdx.x * 256 + threadIdx.x;
    if (e >= E_EDGES) return;
    int src = ei[e];
    int dst = ei[E_EDGES + e];
    float eav[FE];
    load8(ea + (size_t)e * FE, eav);
    float u[IH];
    edge_mlp(eav, w1, b1, u);
    float hv[HID];
    load8(hin + (size_t)src * HID,     hv);
    load8(hin + (size_t)src * HID + 8, hv + 8);
    float msg[IH];
#pragma unroll
    for (int o = 0; o < IH; ++o) msg[o] = 0.f;
#pragma unroll
    for (int i = 0; i < HID; ++i) {
        float hi = hv[i];
#pragma unroll
        for (int o = 0; o < IH; ++o) {
            float t = b2[i*IH + o];
#pragma unroll
            for (int h = 0; h < IH; ++h)
                t = fmaf(u[h], w2[h*(HID*IH) + i*IH + o], t);
            msg[o] = fmaf(hi, t, msg[o]);
        }
    }
    float* ap = agg + (size_t)dst * IH;
#pragma unroll
    for (int o = 0; o < IH; ++o) atomicAdd(ap + o, msg[o]);
}

__global__ __launch_bounds__(256) void node1_k(
    const float* __restrict__ hin, const float* __restrict__ agg,
    const float* __restrict__ root, const float* __restrict__ bias,
    float* __restrict__ h2)
{
    int idx = blockIdx.x * 256 + threadIdx.x;
    if (idx >= N_NODES * IH) return;
    int n = idx / IH;
    int o = idx - n * IH;
    float s = agg[idx] + bias[o];
    const float* hr = hin + (size_t)n * HID;
#pragma unroll
    for (int i = 0; i < HID; ++i) s = fmaf(hr[i], root[i*IH + o], s);
    h2[idx] = fmaxf(s, 0.f);
}

extern "C" void kernel_launch(void* const* d_in, const int* in_sizes, int n_in,
                              void* d_out, int out_size, void* d_ws, size_t ws_size,
                              hipStream_t stream) {
    const float* x       = (const float*)d_in[0];
    const float* ea      = (const float*)d_in[1];
    const int*   ei      = (const int*)  d_in[2];
    const float* c0_w1   = (const float*)d_in[3];
    const float* c0_b1   = (const float*)d_in[4];
    const float* c0_w2   = (const float*)d_in[5];
    const float* c0_b2   = (const float*)d_in[6];
    const float* c0_root = (const float*)d_in[7];
    const float* c0_bias = (const float*)d_in[8];
    const float* c1_w1   = (const float*)d_in[9];
    const float* c1_b1   = (const float*)d_in[10];
    const float* c1_w2   = (const float*)d_in[11];
    const float* c1_b2   = (const float*)d_in[12];
    const float* c1_root = (const float*)d_in[13];
    const float* c1_bias = (const float*)d_in[14];
    const float* ep_w1   = (const float*)d_in[15];
    const float* ep_b1   = (const float*)d_in[16];
    const float* ep_w2   = (const float*)d_in[17];
    const float* ep_b2   = (const float*)d_in[18];
    float* out = (float*)d_out;

    int eb = (E_EDGES + 255) / 256;

    if (ws_size >= WS_NEED) {
        int*   wi     = (int*)d_ws;
        int*   cnt    = wi + I_CNT;
        int*   offset = wi + I_OFF;
        int*   rank   = wi + I_RANK;
        int*   bsum   = wi + I_BSUM;
        int*   bbase  = wi + I_BBASE;
        float* wf     = (float*)(wi + I_TOTAL);
        float* h      = wf + F_H;
        float* h2     = wf + F_H2;
        float* msg    = wf + F_MSG;

        hipMemsetAsync(cnt, 0, N_NODES * sizeof(int), stream);
        count_rank_k<<<eb, 256, 0, stream>>>(ei, cnt, rank);
        blocksum_k<<<NB_SCAN, 256, 0, stream>>>(cnt, bsum);
        scan_bsums_k<<<1, 256, 0, stream>>>(bsum, bbase);
        offsets_k<<<NB_SCAN, 256, 0, stream>>>(cnt, bbase, offset);

        conv0_osplit_k<<<E_EDGES/256, 256, 0, stream>>>(x, ea, ei, c0_w1, c0_b1,
                                                        c0_w2, c0_b2, offset, rank, msg);
        node0_red_k<<<(N_NODES*HID + 255)/256, 256, 0, stream>>>(x, msg, offset,
                                                                 c0_root, c0_bias, h);
        conv1_osplit_k<<<(E_EDGES + C1_TILE - 1)/C1_TILE, 256, 0, stream>>>(
            h, ea, ei, c1_w1, c1_b1, c1_w2, c1_b2, offset, rank, msg);
        node1_red_k<<<(N_NODES*IH + 255)/256, 256, 0, stream>>>(h, msg, offset,
                                                                c1_root, c1_bias, h2);
        edge_pred_k<<<eb, 256, 0, stream>>>(h2, ea, ei, ep_w1, ep_b1, ep_w2, ep_b2, out);
    } else {
        float* ws   = (float*)d_ws;
        float* agg0 = ws;
        float* agg1 = ws + 800000;
        float* h    = ws + 1300000;
        float* h2   = ws + 2100000;
        hipMemsetAsync(d_ws, 0, 1300000 * sizeof(float), stream);
        conv0_edge_k<<<eb, 256, 0, stream>>>(x, ea, ei, c0_w1, c0_b1, c0_w2, c0_b2, agg0);
        node0_k<<<(N_NODES*HID + 255)/256, 256, 0, stream>>>(x, agg0, c0_root, c0_bias, h);
        conv1_edge_k<<<eb, 256, 0, stream>>>(h, ea, ei, c1_w1, c1_b1, c1_w2, c1_b2, agg1);
        node1_k<<<(N_NODES*IH + 255)/256, 256, 0, stream>>>(h, agg1, c1_root, c1_bias, h2);
        edge_pred_k<<<eb, 256, 0, stream>>>(h2, ea, ei, ep_w1, ep_b1, ep_w2, ep_b2, out);
    }
}

// Round 7
// 300.060 us; speedup vs baseline: 1.3373x; 1.1464x over previous
//
#include <hip/hip_runtime.h>

#define N_NODES 50000
#define E_EDGES 1600000
#define FN 8
#define FE 8
#define HID 16
#define IH 10
#define NB_SCAN 196   // ceil(50000/256)

// ---------------- workspace layout ----------------
#define I_CNT   0
#define I_OFF   50048
#define I_RANK  100096
#define I_BSUM  1700096
#define I_BBASE 1700352
#define I_TOTAL 1700608
#define F_H     0
#define F_H2    800000
#define F_MSG   1300000
#define F_TOTAL 26900000
#define WS_NEED ((size_t)I_TOTAL*4 + (size_t)F_TOTAL*4)

// ================= CSR build =================
__global__ __launch_bounds__(256) void count_rank_k(
    const int* __restrict__ ei, int* __restrict__ cnt, int* __restrict__ rank)
{
    int e = blockIdx.x * 256 + threadIdx.x;
    if (e >= E_EDGES) return;
    int dst = ei[E_EDGES + e];
    rank[e] = atomicAdd(&cnt[dst], 1);
}

__global__ __launch_bounds__(256) void blocksum_k(
    const int* __restrict__ cnt, int* __restrict__ bsum)
{
    __shared__ int sh[256];
    int t = threadIdx.x;
    int idx = blockIdx.x * 256 + t;
    sh[t] = (idx < N_NODES) ? cnt[idx] : 0;
    __syncthreads();
#pragma unroll
    for (int d = 128; d > 0; d >>= 1) {
        if (t < d) sh[t] += sh[t + d];
        __syncthreads();
    }
    if (t == 0) bsum[blockIdx.x] = sh[0];
}

__global__ __launch_bounds__(256) void scan_bsums_k(
    const int* __restrict__ bsum, int* __restrict__ bbase)
{
    __shared__ int sh[256];
    int t = threadIdx.x;
    int v = (t < NB_SCAN) ? bsum[t] : 0;
    sh[t] = v;
    __syncthreads();
#pragma unroll
    for (int d = 1; d < 256; d <<= 1) {
        int u = (t >= d) ? sh[t - d] : 0;
        __syncthreads();
        sh[t] += u;
        __syncthreads();
    }
    if (t < NB_SCAN) bbase[t] = sh[t] - v;
}

__global__ __launch_bounds__(256) void offsets_k(
    const int* __restrict__ cnt, const int* __restrict__ bbase,
    int* __restrict__ offset)
{
    __shared__ int sh[256];
    int t = threadIdx.x;
    int b = blockIdx.x;
    int idx = b * 256 + t;
    int v = (idx < N_NODES) ? cnt[idx] : 0;
    sh[t] = v;
    __syncthreads();
#pragma unroll
    for (int d = 1; d < 256; d <<= 1) {
        int u = (t >= d) ? sh[t - d] : 0;
        __syncthreads();
        sh[t] += u;
        __syncthreads();
    }
    int incl = sh[t];
    int base = bbase[b];
    if (idx < N_NODES) offset[idx] = base + incl - v;
    if (idx == N_NODES - 1) offset[N_NODES] = base + incl;
}

// ================= helpers =================
__device__ __forceinline__ void load8(const float* __restrict__ p, float v[8]) {
    const float4* q = reinterpret_cast<const float4*>(p);
    float4 a = q[0], b = q[1];
    v[0]=a.x; v[1]=a.y; v[2]=a.z; v[3]=a.w;
    v[4]=b.x; v[5]=b.y; v[6]=b.z; v[7]=b.w;
}

// edge MLP, k-outer so w1 [FE][IH] is walked sequentially
__device__ __forceinline__ void edge_mlp_seq(
    const float eav[FE], const float* __restrict__ w1,
    const float* __restrict__ b1, float u[IH])
{
#pragma unroll
    for (int h = 0; h < IH; ++h) u[h] = b1[h];
#pragma unroll
    for (int k = 0; k < FE; ++k) {
        float ek = eav[k];
#pragma unroll
        for (int h = 0; h < IH; ++h) u[h] = fmaf(ek, w1[k*IH + h], u[h]);
    }
#pragma unroll
    for (int h = 0; h < IH; ++h) u[h] = fmaxf(u[h], 0.f);
}

// ================= conv0: 1 edge/thread, sequential weight streaming =================
// msg[o] = sum_i x[i]*b2[i][o] + sum_h u[h]*(sum_i x[i]*w2[h][i][o])
__global__ __launch_bounds__(256) void conv0_scatter_k(
    const float* __restrict__ x, const float* __restrict__ ea,
    const int* __restrict__ ei,
    const float* __restrict__ w1, const float* __restrict__ b1,
    const float* __restrict__ w2, const float* __restrict__ b2,
    const int* __restrict__ offset, const int* __restrict__ rank,
    float* __restrict__ msgbuf)          // [E][16]
{
    int e = blockIdx.x * 256 + threadIdx.x;
    if (e >= E_EDGES) return;
    int src = ei[e];
    int dst = ei[E_EDGES + e];

    float eav[FE];
    load8(ea + (size_t)e * FE, eav);
    float u[IH];
    edge_mlp_seq(eav, w1, b1, u);
    float xv[FN];
    load8(x + (size_t)src * FN, xv);

    float msg[HID];
    // b2 panel: [8][16] sequential
#pragma unroll
    for (int o = 0; o < HID; ++o) msg[o] = 0.f;
#pragma unroll
    for (int i = 0; i < FN; ++i) {
        float xi = xv[i];
#pragma unroll
        for (int o = 0; o < HID; ++o)
            msg[o] = fmaf(xi, b2[i*HID + o], msg[o]);
    }
    // w2 panels: for each h, [8][16] = 128 floats sequential
#pragma unroll
    for (int h = 0; h < IH; ++h) {
        float t[HID];
#pragma unroll
        for (int o = 0; o < HID; ++o) t[o] = 0.f;
        const float* wp = w2 + h * (FN*HID);
#pragma unroll
        for (int i = 0; i < FN; ++i) {
            float xi = xv[i];
#pragma unroll
            for (int o = 0; o < HID; ++o)
                t[o] = fmaf(xi, wp[i*HID + o], t[o]);
        }
        float uh = u[h];
#pragma unroll
        for (int o = 0; o < HID; ++o) msg[o] = fmaf(uh, t[o], msg[o]);
    }

    size_t pos = (size_t)(offset[dst] + rank[e]) * HID;
    float4* mp = reinterpret_cast<float4*>(msgbuf + pos);
    mp[0] = make_float4(msg[0],  msg[1],  msg[2],  msg[3]);
    mp[1] = make_float4(msg[4],  msg[5],  msg[6],  msg[7]);
    mp[2] = make_float4(msg[8],  msg[9],  msg[10], msg[11]);
    mp[3] = make_float4(msg[12], msg[13], msg[14], msg[15]);
}

// ================= node0: segmented reduce + root + relu =================
__global__ __launch_bounds__(256) void node0_red_k(
    const float* __restrict__ x, const float* __restrict__ msgbuf,
    const int* __restrict__ offset,
    const float* __restrict__ root, const float* __restrict__ bias,
    float* __restrict__ h)
{
    int idx = blockIdx.x * 256 + threadIdx.x;
    if (idx >= N_NODES * HID) return;
    int n = idx >> 4;
    int o = idx & 15;
    int beg = offset[n], end = offset[n + 1];
    float s = bias[o];
    for (int j = beg; j < end; ++j) s += msgbuf[(size_t)j * HID + o];
    const float* xr = x + (size_t)n * FN;
#pragma unroll
    for (int i = 0; i < FN; ++i) s = fmaf(xr[i], root[i*HID + o], s);
    h[idx] = fmaxf(s, 0.f);
}

// ================= conv1: 1 edge/thread, sequential weight streaming =================
__global__ __launch_bounds__(256) void conv1_scatter_k(
    const float* __restrict__ hin, const float* __restrict__ ea,
    const int* __restrict__ ei,
    const float* __restrict__ w1, const float* __restrict__ b1,
    const float* __restrict__ w2, const float* __restrict__ b2,
    const int* __restrict__ offset, const int* __restrict__ rank,
    float* __restrict__ msgbuf)          // [E][10]
{
    int e = blockIdx.x * 256 + threadIdx.x;
    if (e >= E_EDGES) return;
    int src = ei[e];
    int dst = ei[E_EDGES + e];

    float eav[FE];
    load8(ea + (size_t)e * FE, eav);
    float u[IH];
    edge_mlp_seq(eav, w1, b1, u);
    float hv[HID];
    load8(hin + (size_t)src * HID,     hv);
    load8(hin + (size_t)src * HID + 8, hv + 8);

    float msg[IH];
#pragma unroll
    for (int o = 0; o < IH; ++o) msg[o] = 0.f;
    // b2 panel: [16][10] sequential
#pragma unroll
    for (int i = 0; i < HID; ++i) {
        float hi = hv[i];
#pragma unroll
        for (int o = 0; o < IH; ++o)
            msg[o] = fmaf(hi, b2[i*IH + o], msg[o]);
    }
    // w2 panels: for each hh, [16][10] = 160 floats sequential
#pragma unroll
    for (int hh = 0; hh < IH; ++hh) {
        float t[IH];
#pragma unroll
        for (int o = 0; o < IH; ++o) t[o] = 0.f;
        const float* wp = w2 + hh * (HID*IH);
#pragma unroll
        for (int i = 0; i < HID; ++i) {
            float hi = hv[i];
#pragma unroll
            for (int o = 0; o < IH; ++o)
                t[o] = fmaf(hi, wp[i*IH + o], t[o]);
        }
        float uh = u[hh];
#pragma unroll
        for (int o = 0; o < IH; ++o) msg[o] = fmaf(uh, t[o], msg[o]);
    }

    size_t pos = (size_t)(offset[dst] + rank[e]) * IH;
    float2* mp = reinterpret_cast<float2*>(msgbuf + pos);
    mp[0] = make_float2(msg[0], msg[1]);
    mp[1] = make_float2(msg[2], msg[3]);
    mp[2] = make_float2(msg[4], msg[5]);
    mp[3] = make_float2(msg[6], msg[7]);
    mp[4] = make_float2(msg[8], msg[9]);
}

// ================= node1: segmented reduce + root + relu =================
__global__ __launch_bounds__(256) void node1_red_k(
    const float* __restrict__ hin, const float* __restrict__ msgbuf,
    const int* __restrict__ offset,
    const float* __restrict__ root, const float* __restrict__ bias,
    float* __restrict__ h2)
{
    int idx = blockIdx.x * 256 + threadIdx.x;
    if (idx >= N_NODES * IH) return;
    int n = idx / IH;
    int o = idx - n * IH;
    int beg = offset[n], end = offset[n + 1];
    float s = bias[o];
    for (int j = beg; j < end; ++j) s += msgbuf[(size_t)j * IH + o];
    const float* hr = hin + (size_t)n * HID;
#pragma unroll
    for (int i = 0; i < HID; ++i) s = fmaf(hr[i], root[i*IH + o], s);
    h2[idx] = fmaxf(s, 0.f);
}

// ================= edge predictor: sequential w1 streaming =================
__global__ __launch_bounds__(256) void edge_pred_k(
    const float* __restrict__ h2, const float* __restrict__ ea,
    const int* __restrict__ ei,
    const float* __restrict__ w1, const float* __restrict__ b1,
    const float* __restrict__ w2, const float* __restrict__ b2,
    float* __restrict__ out)
{
    int e = blockIdx.x * 256 + threadIdx.x;
    if (e >= E_EDGES) return;
    int src = ei[e];
    float eav[FE];
    load8(ea + (size_t)e * FE, eav);
    float hv[IH];
    {
        const float2* p = reinterpret_cast<const float2*>(h2 + (size_t)src * IH);
        float2 a = p[0], b = p[1], c = p[2], d = p[3], f = p[4];
        hv[0]=a.x; hv[1]=a.y; hv[2]=b.x; hv[3]=b.y; hv[4]=c.x;
        hv[5]=c.y; hv[6]=d.x; hv[7]=d.y; hv[8]=f.x; hv[9]=f.y;
    }
    float t[IH];
#pragma unroll
    for (int j = 0; j < IH; ++j) t[j] = b1[j];
#pragma unroll
    for (int k = 0; k < FE; ++k) {
        float ek = eav[k];
#pragma unroll
        for (int j = 0; j < IH; ++j) t[j] = fmaf(ek, w1[k*IH + j], t[j]);
    }
#pragma unroll
    for (int k = 0; k < IH; ++k) {
        float hk = hv[k];
#pragma unroll
        for (int j = 0; j < IH; ++j) t[j] = fmaf(hk, w1[(FE + k)*IH + j], t[j]);
    }
    float score = b2[0];
#pragma unroll
    for (int j = 0; j < IH; ++j)
        score = fmaf(fmaxf(t[j], 0.f), w2[j], score);
    out[e] = score;
}

// ================= fallback (atomic) path =================
__global__ __launch_bounds__(256) void conv0_edge_k(
    const float* __restrict__ x, const float* __restrict__ ea,
    const int* __restrict__ ei,
    const float* __restrict__ w1, const float* __restrict__ b1,
    const float* __restrict__ w2, const float* __restrict__ b2,
    float* __restrict__ agg)
{
    int e = blockIdx.x * 256 + threadIdx.x;
    if (e >= E_EDGES) return;
    int src = ei[e];
    int dst = ei[E_EDGES + e];
    float eav[FE];
    load8(ea + (size_t)e * FE, eav);
    float u[IH];
    edge_mlp_seq(eav, w1, b1, u);
    float xv[FN];
    load8(x + (size_t)src * FN, xv);
    float msg[HID];
#pragma unroll
    for (int o = 0; o < HID; ++o) msg[o] = 0.f;
#pragma unroll
    for (int i = 0; i < FN; ++i) {
        float xi = xv[i];
#pragma unroll
        for (int o = 0; o < HID; ++o)
            msg[o] = fmaf(xi, b2[i*HID + o], msg[o]);
    }
#pragma unroll
    for (int h = 0; h < IH; ++h) {
        float t[HID];
#pragma unroll
        for (int o = 0; o < HID; ++o) t[o] = 0.f;
        const float* wp = w2 + h * (FN*HID);
#pragma unroll
        for (int i = 0; i < FN; ++i) {
            float xi = xv[i];
#pragma unroll
            for (int o = 0; o < HID; ++o)
                t[o] = fmaf(xi, wp[i*HID + o], t[o]);
        }
        float uh = u[h];
#pragma unroll
        for (int o = 0; o < HID; ++o) msg[o] = fmaf(uh, t[o], msg[o]);
    }
    float* ap = agg + (size_t)dst * HID;
#pragma unroll
    for (int o = 0; o < HID; ++o) atomicAdd(ap + o, msg[o]);
}

__global__ __launch_bounds__(256) void node0_k(
    const float* __restrict__ x, const float* __restrict__ agg,
    const float* __restrict__ root, const float* __restrict__ bias,
    float* __restrict__ h)
{
    int idx = blockIdx.x * 256 + threadIdx.x;
    if (idx >= N_NODES * HID) return;
    int n = idx >> 4;
    int o = idx & 15;
    float s = agg[idx] + bias[o];
    const float* xr = x + (size_t)n * FN;
#pragma unroll
    for (int i = 0; i < FN; ++i) s = fmaf(xr[i], root[i*HID + o], s);
    h[idx] = fmaxf(s, 0.f);
}

__global__ __launch_bounds__(256) void conv1_edge_k(
    const float* __restrict__ hin, const float* __restrict__ ea,
    const int* __restrict__ ei,
    const float* __restrict__ w1, const float* __restrict__ b1,
    const float* __restrict__ w2, const float* __restrict__ b2,
    float* __restrict__ agg)
{
    int e = blockIdx.x * 256 + threadIdx.x;
    if (e >= E_EDGES) return;
    int src = ei[e];
    int dst = ei[E_EDGES + e];
    float eav[FE];
    load8(ea + (size_t)e * FE, eav);
    float u[IH];
    edge_mlp_seq(eav, w1, b1, u);
    float hv[HID];
    load8(hin + (size_t)src * HID,     hv);
    load8(hin + (size_t)src * HID + 8, hv + 8);
    float msg[IH];
#pragma unroll
    for (int o = 0; o < IH; ++o) msg[o] = 0.f;
#pragma unroll
    for (int i = 0; i < HID; ++i) {
        float hi = hv[i];
#pragma unroll
        for (int o = 0; o < IH; ++o)
            msg[o] = fmaf(hi, b2[i*IH + o], msg[o]);
    }
#pragma unroll
    for (int hh = 0; hh < IH; ++hh) {
        float t[IH];
#pragma unroll
        for (int o = 0; o < IH; ++o) t[o] = 0.f;
        const float* wp = w2 + hh * (HID*IH);
#pragma unroll
        for (int i = 0; i < HID; ++i) {
            float hi = hv[i];
#pragma unroll
            for (int o = 0; o < IH; ++o)
                t[o] = fmaf(hi, wp[i*IH + o], t[o]);
        }
        float uh = u[hh];
#pragma unroll
        for (int o = 0; o < IH; ++o) msg[o] = fmaf(uh, t[o], msg[o]);
    }
    float* ap = agg + (size_t)dst * IH;
#pragma unroll
    for (int o = 0; o < IH; ++o) atomicAdd(ap + o, msg[o]);
}

__global__ __launch_bounds__(256) void node1_k(
    const float* __restrict__ hin, const float* __restrict__ agg,
    const float* __restrict__ root, const float* __restrict__ bias,
    float* __restrict__ h2)
{
    int idx = blockIdx.x * 256 + threadIdx.x;
    if (idx >= N_NODES * IH) return;
    int n = idx / IH;
    int o = idx - n * IH;
    float s = agg[idx] + bias[o];
    const float* hr = hin + (size_t)n * HID;
#pragma unroll
    for (int i = 0; i < HID; ++i) s = fmaf(hr[i], root[i*IH + o], s);
    h2[idx] = fmaxf(s, 0.f);
}

extern "C" void kernel_launch(void* const* d_in, const int* in_sizes, int n_in,
                              void* d_out, int out_size, void* d_ws, size_t ws_size,
                              hipStream_t stream) {
    const float* x       = (const float*)d_in[0];
    const float* ea      = (const float*)d_in[1];
    const int*   ei      = (const int*)  d_in[2];
    const float* c0_w1   = (const float*)d_in[3];
    const float* c0_b1   = (const float*)d_in[4];
    const float* c0_w2   = (const float*)d_in[5];
    const float* c0_b2   = (const float*)d_in[6];
    const float* c0_root = (const float*)d_in[7];
    const float* c0_bias = (const float*)d_in[8];
    const float* c1_w1   = (const float*)d_in[9];
    const float* c1_b1   = (const float*)d_in[10];
    const float* c1_w2   = (const float*)d_in[11];
    const float* c1_b2   = (const float*)d_in[12];
    const float* c1_root = (const float*)d_in[13];
    const float* c1_bias = (const float*)d_in[14];
    const float* ep_w1   = (const float*)d_in[15];
    const float* ep_b1   = (const float*)d_in[16];
    const float* ep_w2   = (const float*)d_in[17];
    const float* ep_b2   = (const float*)d_in[18];
    float* out = (float*)d_out;

    int eb = (E_EDGES + 255) / 256;

    if (ws_size >= WS_NEED) {
        int*   wi     = (int*)d_ws;
        int*   cnt    = wi + I_CNT;
        int*   offset = wi + I_OFF;
        int*   rank   = wi + I_RANK;
        int*   bsum   = wi + I_BSUM;
        int*   bbase  = wi + I_BBASE;
        float* wf     = (float*)(wi + I_TOTAL);
        float* h      = wf + F_H;
        float* h2     = wf + F_H2;
        float* msg    = wf + F_MSG;

        hipMemsetAsync(cnt, 0, N_NODES * sizeof(int), stream);
        count_rank_k<<<eb, 256, 0, stream>>>(ei, cnt, rank);
        blocksum_k<<<NB_SCAN, 256, 0, stream>>>(cnt, bsum);
        scan_bsums_k<<<1, 256, 0, stream>>>(bsum, bbase);
        offsets_k<<<NB_SCAN, 256, 0, stream>>>(cnt, bbase, offset);

        conv0_scatter_k<<<eb, 256, 0, stream>>>(x, ea, ei, c0_w1, c0_b1, c0_w2, c0_b2,
                                                offset, rank, msg);
        node0_red_k<<<(N_NODES*HID + 255)/256, 256, 0, stream>>>(x, msg, offset,
                                                                 c0_root, c0_bias, h);
        conv1_scatter_k<<<eb, 256, 0, stream>>>(h, ea, ei, c1_w1, c1_b1, c1_w2, c1_b2,
                                                offset, rank, msg);
        node1_red_k<<<(N_NODES*IH + 255)/256, 256, 0, stream>>>(h, msg, offset,
                                                                c1_root, c1_bias, h2);
        edge_pred_k<<<eb, 256, 0, stream>>>(h2, ea, ei, ep_w1, ep_b1, ep_w2, ep_b2, out);
    } else {
        float* ws   = (float*)d_ws;
        float* agg0 = ws;
        float* agg1 = ws + 800000;
        float* h    = ws + 1300000;
        float* h2   = ws + 2100000;
        hipMemsetAsync(d_ws, 0, 1300000 * sizeof(float), stream);
        conv0_edge_k<<<eb, 256, 0, stream>>>(x, ea, ei, c0_w1, c0_b1, c0_w2, c0_b2, agg0);
        node0_k<<<(N_NODES*HID + 255)/256, 256, 0, stream>>>(x, agg0, c0_root, c0_bias, h);
        conv1_edge_k<<<eb, 256, 0, stream>>>(h, ea, ei, c1_w1, c1_b1, c1_w2, c1_b2, agg1);
        node1_k<<<(N_NODES*IH + 255)/256, 256, 0, stream>>>(h, agg1, c1_root, c1_bias, h2);
        edge_pred_k<<<eb, 256, 0, stream>>>(h2, ea, ei, ep_w1, ep_b1, ep_w2, ep_b2, out);
    }
}